// Round 3
// baseline (1142.803 us; speedup 1.0000x reference)
//
#include <hip/hip_runtime.h>
#include <hip/hip_bf16.h>
#include <stdint.h>

#define BATCH  1024
#define DIM    1024
#define NKH    65536
#define HID    1024
#define PSTR   32768   // panel stride in elements: 1024 rows * 32 slots

// (BETA / sqrt(DIM)) * log2(e) = 0.25 * 1.4426950408889634
#define SC1 0.36067376022224085f

typedef __bf16 bf16x8 __attribute__((ext_vector_type(8)));
typedef float  f32x4  __attribute__((ext_vector_type(4)));

__device__ __forceinline__ unsigned short f2bf(float f) {
  union { float f; unsigned int u; } v; v.f = f;
  unsigned int r = v.u + 0x7fffu + ((v.u >> 16) & 1u);
  return (unsigned short)(r >> 16);
}
__device__ __forceinline__ float bf2f(unsigned short s) {
  union { unsigned int u; float f; } v; v.u = ((unsigned int)s) << 16;
  return v.f;
}
__device__ __forceinline__ unsigned int pk2(float lo, float hi) {
  union { __hip_bfloat162 h; unsigned int u; } v;
  v.h = __float22bfloat162_rn(make_float2(lo, hi));
  return v.u;
}
__device__ __forceinline__ void gl2lds16(const void* g, void* l) {
  __builtin_amdgcn_global_load_lds(
      (const __attribute__((address_space(1))) void*)g,
      (__attribute__((address_space(3))) void*)l, 16, 0, 0);
}

// ---------------------------------------------------------------------------
// fp32 -> bf16 cast, 8 elements/thread
// ---------------------------------------------------------------------------
__global__ __launch_bounds__(256) void k_cast(
    const float* __restrict__ s, unsigned short* __restrict__ d, int n8) {
  int i = blockIdx.x * 256 + threadIdx.x;
  if (i >= n8) return;
  float4 a = ((const float4*)s)[(size_t)i * 2];
  float4 b = ((const float4*)s)[(size_t)i * 2 + 1];
  uint4 o;
  o.x = pk2(a.x, a.y); o.y = pk2(a.z, a.w);
  o.z = pk2(b.x, b.y); o.w = pk2(b.z, b.w);
  ((uint4*)d)[i] = o;
}

// ---------------------------------------------------------------------------
// values [65536,1024] fp32 -> V_blk[nk/32][j][nk%32] bf16 (K-panel blocked)
// ---------------------------------------------------------------------------
__global__ __launch_bounds__(256) void k_transpose_cast(
    const float* __restrict__ V, unsigned short* __restrict__ Vb) {
  __shared__ float tile[64][65];  // +1 pad: conflict-free transposed reads
  const int t = threadIdx.x;
  const int nk0 = blockIdx.x * 64;
  const int j0  = blockIdx.y * 64;
  #pragma unroll
  for (int i = 0; i < 4; ++i) {
    int idx = t + i * 256;
    int row = idx >> 4, c4 = (idx & 15) << 2;
    float4 v = *(const float4*)(V + (size_t)(nk0 + row) * HID + (j0 + c4));
    tile[row][c4 + 0] = v.x; tile[row][c4 + 1] = v.y;
    tile[row][c4 + 2] = v.z; tile[row][c4 + 3] = v.w;
  }
  __syncthreads();
  const int q = t & 7, jj = t >> 3;
  const int panel = (nk0 >> 5) + (q >> 2);
  const int slot  = (q & 3) * 8;
  #pragma unroll
  for (int i = 0; i < 2; ++i) {
    int j = jj + i * 32;
    uint4 o;
    o.x = pk2(tile[q*8+0][j], tile[q*8+1][j]);
    o.y = pk2(tile[q*8+2][j], tile[q*8+3][j]);
    o.z = pk2(tile[q*8+4][j], tile[q*8+5][j]);
    o.w = pk2(tile[q*8+6][j], tile[q*8+7][j]);
    *(uint4*)(Vb + (size_t)panel * PSTR + (size_t)(j0 + j) * 32 + slot) = o;
  }
}

// ---------------------------------------------------------------------------
// GEMM1: E[b,n] = exp2(SC1 * x[b,:]·keys[n,:]) -> E_blk[n/32][b][n%32]
// m97 structure: global_load_lds width-16, 128x128 tile, BK=32, 4 waves 2x2.
// ---------------------------------------------------------------------------
__global__ __launch_bounds__(256) void k_gemm1_exp(
    const unsigned short* __restrict__ Xb, const unsigned short* __restrict__ Kb,
    unsigned short* __restrict__ E) {
  __shared__ __align__(16) unsigned short As[128 * 32];
  __shared__ __align__(16) unsigned short Bs[128 * 32];
  const int t = threadIdx.x;
  const int bm = blockIdx.x & 7, bn = blockIdx.x >> 3;  // bm fastest: share B-tile
  const int m0 = bm << 7, n0 = bn << 7;
  const int lane = t & 63, wave = t >> 6;
  const int wm = (wave >> 1) << 6, wn = (wave & 1) << 6;
  const int r16 = lane & 15, quad = lane >> 4;
  const int srow = lane >> 2, kseg = (lane & 3) * 8;
  const int c0 = wave * 2, c1 = wave * 2 + 1;
  const unsigned short* gA0 = Xb + (size_t)(m0 + c0*16 + srow) * DIM + kseg;
  const unsigned short* gA1 = Xb + (size_t)(m0 + c1*16 + srow) * DIM + kseg;
  const unsigned short* gB0 = Kb + (size_t)(n0 + c0*16 + srow) * DIM + kseg;
  const unsigned short* gB1 = Kb + (size_t)(n0 + c1*16 + srow) * DIM + kseg;
  f32x4 acc[4][4] = {};
  for (int ks = 0; ks < DIM; ks += 32) {
    __syncthreads();
    gl2lds16(gA0 + ks, As + c0 * 512);
    gl2lds16(gA1 + ks, As + c1 * 512);
    gl2lds16(gB0 + ks, Bs + c0 * 512);
    gl2lds16(gB1 + ks, Bs + c1 * 512);
    __syncthreads();
    bf16x8 af[4], bfr[4];
    #pragma unroll
    for (int mi = 0; mi < 4; ++mi)
      af[mi] = *(const bf16x8*)(As + (wm + mi*16 + r16) * 32 + quad * 8);
    #pragma unroll
    for (int ni = 0; ni < 4; ++ni)
      bfr[ni] = *(const bf16x8*)(Bs + (wn + ni*16 + r16) * 32 + quad * 8);
    #pragma unroll
    for (int mi = 0; mi < 4; ++mi)
      #pragma unroll
      for (int ni = 0; ni < 4; ++ni)
        acc[mi][ni] = __builtin_amdgcn_mfma_f32_16x16x32_bf16(af[mi], bfr[ni], acc[mi][ni], 0, 0, 0);
  }
  // C/D layout: col = lane&15, row = quad*4 + reg; store into blocked E
  #pragma unroll
  for (int mi = 0; mi < 4; ++mi) {
    #pragma unroll
    for (int ni = 0; ni < 4; ++ni) {
      #pragma unroll
      for (int v = 0; v < 4; ++v) {
        int row = m0 + wm + mi*16 + quad*4 + v;
        int col = n0 + wn + ni*16 + r16;
        E[(size_t)(col >> 5) * PSTR + (size_t)row * 32 + (col & 31)] =
            f2bf(exp2f(acc[mi][ni][v] * SC1));
      }
    }
  }
}

// ---------------------------------------------------------------------------
// Denom stage 1: r_acc[b,h] += sum over panel-chunk (atomic, fp32)
// grid = 16 b-chunks x 16 panel-chunks; coalesced panel-order reads.
// ---------------------------------------------------------------------------
__global__ __launch_bounds__(256) void k_row_denom(
    const unsigned short* __restrict__ E, float* __restrict__ r_acc) {
  __shared__ float acc[64][16];
  const int t = threadIdx.x;
  const int b0 = (blockIdx.x & 15) * 64;
  const int p0 = (blockIdx.x >> 4) * 128;
  for (int i = t; i < 1024; i += 256) ((float*)acc)[i] = 0.0f;
  const int rloc = t >> 2;             // 0..63
  const int kk0  = (t & 3) * 8;        // 0,8,16,24
  const int hb   = (t & 1) * 8;        // head base
  const unsigned short* base = E + (size_t)(b0 + rloc) * 32 + kk0;
  float s[8] = {};
  for (int p = 0; p < 128; ++p) {
    uint4 u = *(const uint4*)(base + (size_t)(p0 + p) * PSTR);
    s[0] += bf2f((unsigned short)(u.x & 0xffff)); s[1] += bf2f((unsigned short)(u.x >> 16));
    s[2] += bf2f((unsigned short)(u.y & 0xffff)); s[3] += bf2f((unsigned short)(u.y >> 16));
    s[4] += bf2f((unsigned short)(u.z & 0xffff)); s[5] += bf2f((unsigned short)(u.z >> 16));
    s[6] += bf2f((unsigned short)(u.w & 0xffff)); s[7] += bf2f((unsigned short)(u.w >> 16));
  }
  __syncthreads();
  #pragma unroll
  for (int j = 0; j < 8; ++j) atomicAdd(&acc[rloc][hb + j], s[j]);
  __syncthreads();
  for (int i = t; i < 1024; i += 256) {
    int rl = i >> 4, h = i & 15;
    atomicAdd(&r_acc[(b0 + rl) * 16 + h], acc[rl][h]);
  }
}

// r = 1 / r_acc  (16384 elements)
__global__ __launch_bounds__(256) void k_recip(
    const float* __restrict__ r_acc, float* __restrict__ r) {
  int i = blockIdx.x * 256 + threadIdx.x;
  r[i] = 1.0f / r_acc[i];
}

// ---------------------------------------------------------------------------
// P = E * r[b, h]  in place on blocked layout; one block per panel.
// ---------------------------------------------------------------------------
__global__ __launch_bounds__(256) void k_scale(
    unsigned short* __restrict__ E, const float* __restrict__ r) {
  const int t = threadIdx.x;
  unsigned short* panel = E + (size_t)blockIdx.x * PSTR;
  #pragma unroll
  for (int i = 0; i < 4; ++i) {
    int row = i * 256 + t;
    const float4* rp = (const float4*)(r + row * 16);
    float4 r0 = rp[0], r1 = rp[1], r2 = rp[2], r3 = rp[3];
    uint4* dp = (uint4*)(panel + (size_t)row * 32);
    uint4 u0 = dp[0], u1 = dp[1], u2 = dp[2], u3 = dp[3];
    uint4 o0, o1, o2, o3;
    o0.x = pk2(bf2f((unsigned short)(u0.x & 0xffff)) * r0.x, bf2f((unsigned short)(u0.x >> 16)) * r0.y);
    o0.y = pk2(bf2f((unsigned short)(u0.y & 0xffff)) * r0.z, bf2f((unsigned short)(u0.y >> 16)) * r0.w);
    o0.z = pk2(bf2f((unsigned short)(u0.z & 0xffff)) * r1.x, bf2f((unsigned short)(u0.z >> 16)) * r1.y);
    o0.w = pk2(bf2f((unsigned short)(u0.w & 0xffff)) * r1.z, bf2f((unsigned short)(u0.w >> 16)) * r1.w);
    o1.x = pk2(bf2f((unsigned short)(u1.x & 0xffff)) * r2.x, bf2f((unsigned short)(u1.x >> 16)) * r2.y);
    o1.y = pk2(bf2f((unsigned short)(u1.y & 0xffff)) * r2.z, bf2f((unsigned short)(u1.y >> 16)) * r2.w);
    o1.z = pk2(bf2f((unsigned short)(u1.z & 0xffff)) * r3.x, bf2f((unsigned short)(u1.z >> 16)) * r3.y);
    o1.w = pk2(bf2f((unsigned short)(u1.w & 0xffff)) * r3.z, bf2f((unsigned short)(u1.w >> 16)) * r3.w);
    o2.x = pk2(bf2f((unsigned short)(u2.x & 0xffff)) * r0.x, bf2f((unsigned short)(u2.x >> 16)) * r0.y);
    o2.y = pk2(bf2f((unsigned short)(u2.y & 0xffff)) * r0.z, bf2f((unsigned short)(u2.y >> 16)) * r0.w);
    o2.z = pk2(bf2f((unsigned short)(u2.z & 0xffff)) * r1.x, bf2f((unsigned short)(u2.z >> 16)) * r1.y);
    o2.w = pk2(bf2f((unsigned short)(u2.w & 0xffff)) * r1.z, bf2f((unsigned short)(u2.w >> 16)) * r1.w);
    o3.x = pk2(bf2f((unsigned short)(u3.x & 0xffff)) * r2.x, bf2f((unsigned short)(u3.x >> 16)) * r2.y);
    o3.y = pk2(bf2f((unsigned short)(u3.y & 0xffff)) * r2.z, bf2f((unsigned short)(u3.y >> 16)) * r2.w);
    o3.z = pk2(bf2f((unsigned short)(u3.z & 0xffff)) * r3.x, bf2f((unsigned short)(u3.z >> 16)) * r3.y);
    o3.w = pk2(bf2f((unsigned short)(u3.w & 0xffff)) * r3.z, bf2f((unsigned short)(u3.w >> 16)) * r3.w);
    dp[0] = o0; dp[1] = o1; dp[2] = o2; dp[3] = o3;
  }
}

// ---------------------------------------------------------------------------
// GEMM2: out[b,j] += sum_n P[b,n] * V[j,n]  on blocked panels.
// split-K=16, atomic epilogue; staging reads are contiguous 1KB per wave.
// ---------------------------------------------------------------------------
__global__ __launch_bounds__(256) void k_gemm2(
    const unsigned short* __restrict__ P, const unsigned short* __restrict__ Vb,
    float* __restrict__ out) {
  __shared__ __align__(16) unsigned short As[128 * 32];
  __shared__ __align__(16) unsigned short Bs[128 * 32];
  const int t = threadIdx.x;
  const int bm = blockIdx.x & 7, bn = (blockIdx.x >> 3) & 7, sp = blockIdx.x >> 6;
  const int m0 = bm << 7, n0 = bn << 7;
  const int lane = t & 63, wave = t >> 6;
  const int wm = (wave >> 1) << 6, wn = (wave & 1) << 6;
  const int r16 = lane & 15, quad = lane >> 4;
  const int srow = lane >> 2, kseg = (lane & 3) * 8;
  const int c0 = wave * 2, c1 = wave * 2 + 1;
  const size_t pbase = (size_t)sp * 128 * PSTR;
  const unsigned short* gA0 = P  + pbase + (size_t)(m0 + c0*16 + srow) * 32 + kseg;
  const unsigned short* gA1 = P  + pbase + (size_t)(m0 + c1*16 + srow) * 32 + kseg;
  const unsigned short* gB0 = Vb + pbase + (size_t)(n0 + c0*16 + srow) * 32 + kseg;
  const unsigned short* gB1 = Vb + pbase + (size_t)(n0 + c1*16 + srow) * 32 + kseg;
  f32x4 acc[4][4] = {};
  for (int it = 0; it < 128; ++it) {
    const size_t off = (size_t)it * PSTR;
    __syncthreads();
    gl2lds16(gA0 + off, As + c0 * 512);
    gl2lds16(gA1 + off, As + c1 * 512);
    gl2lds16(gB0 + off, Bs + c0 * 512);
    gl2lds16(gB1 + off, Bs + c1 * 512);
    __syncthreads();
    bf16x8 af[4], bfr[4];
    #pragma unroll
    for (int mi = 0; mi < 4; ++mi)
      af[mi] = *(const bf16x8*)(As + (wm + mi*16 + r16) * 32 + quad * 8);
    #pragma unroll
    for (int ni = 0; ni < 4; ++ni)
      bfr[ni] = *(const bf16x8*)(Bs + (wn + ni*16 + r16) * 32 + quad * 8);
    #pragma unroll
    for (int mi = 0; mi < 4; ++mi)
      #pragma unroll
      for (int ni = 0; ni < 4; ++ni)
        acc[mi][ni] = __builtin_amdgcn_mfma_f32_16x16x32_bf16(af[mi], bfr[ni], acc[mi][ni], 0, 0, 0);
  }
  #pragma unroll
  for (int mi = 0; mi < 4; ++mi) {
    #pragma unroll
    for (int ni = 0; ni < 4; ++ni) {
      #pragma unroll
      for (int v = 0; v < 4; ++v) {
        int row = m0 + wm + mi*16 + quad*4 + v;
        int col = n0 + wn + ni*16 + r16;
        unsafeAtomicAdd(&out[(size_t)row * HID + col], acc[mi][ni][v]);
      }
    }
  }
}

extern "C" void kernel_launch(void* const* d_in, const int* in_sizes, int n_in,
                              void* d_out, int out_size, void* d_ws, size_t ws_size,
                              hipStream_t stream) {
  (void)in_sizes; (void)n_in; (void)out_size; (void)ws_size;
  const float* x      = (const float*)d_in[0];
  const float* keys   = (const float*)d_in[1];
  const float* values = (const float*)d_in[2];
  float* out = (float*)d_out;

  // ws: E_blk 128MB | B2 128MB (Kb, then V_blk) | Xb 2MB | r_acc 64KB | r 64KB
  unsigned short* E  = (unsigned short*)d_ws;
  unsigned short* B2 = E + (size_t)BATCH * NKH;
  unsigned short* Xb = B2 + (size_t)NKH * DIM;
  float* r_acc = (float*)(Xb + (size_t)BATCH * DIM);
  float* r     = r_acc + BATCH * 16;

  hipMemsetAsync(d_out, 0, (size_t)BATCH * HID * sizeof(float), stream);
  hipMemsetAsync(r_acc, 0, BATCH * 16 * sizeof(float), stream);
  k_cast<<<(NKH * (DIM / 8) + 255) / 256, 256, 0, stream>>>(keys, B2, NKH * (DIM / 8));
  k_cast<<<(BATCH * (DIM / 8) + 255) / 256, 256, 0, stream>>>(x, Xb, BATCH * (DIM / 8));
  k_gemm1_exp<<<(BATCH / 128) * (NKH / 128), 256, 0, stream>>>(Xb, B2, E);
  k_row_denom<<<256, 256, 0, stream>>>(E, r_acc);
  k_recip<<<BATCH * 16 / 256, 256, 0, stream>>>(r_acc, r);
  k_scale<<<NKH / 32, 256, 0, stream>>>(E, r);
  // B2 (keys) no longer needed: reuse for V_blk
  k_transpose_cast<<<dim3(NKH / 64, HID / 64), 256, 0, stream>>>(values, B2);
  k_gemm2<<<(BATCH / 128) * (HID / 128) * 16, 256, 0, stream>>>(E, B2, out);
}